// Round 8
// baseline (85.124 us; speedup 1.0000x reference)
//
#include <hip/hip_runtime.h>
#include <cmath>

#define T_STEPS 384
#define CH 64
#define NCH 6
#define WS 392   // replica stride; 392 % 32 == 8 -> ascending per-lane b128 tiles all banks

__device__ __forceinline__ float readlane_f(float v, int l) {
    return __int_as_float(__builtin_amdgcn_readlane(__float_as_int(v), l));
}

// DPP wave shift-right by 1: dst lane i = src lane i-1, lane 0 = 0 (bound_ctrl).
// Marches the near-field weight window one lane per step with ZERO memory ops.
__device__ __forceinline__ float wave_shr1_f(float v) {
    return __int_as_float(__builtin_amdgcn_mov_dpp(__float_as_int(v), 0x138, 0xf, 0xf, true));
}

// One wave per neuron; lane l owns step cb+l of the current 64-step chunk.
// KEY CHANGE vs R6/R7: the near-field scatter weight wr[lane-i] is NOT an
// array (wloc[64] was being spilled to scratch -- the compiler caps VGPRs at
// 128, and scratch loads in the 384-step serial loop were the ~250 cyc/step
// floor). Identity: the weight lane l needs at step i+1 is what lane l-1 held
// at step i -> keep it as ONE register marched by v_mov_b32_dpp wave_shr:1
// (bound_ctrl shifts in 0 = the wr[<=0]=0 mask), reset to w0=wr[lane] per
// chunk. Step body = 9 pure VALU ops, no LDS/scratch. Far field unchanged
// from R6 (bit-identical fma order; conflict-free ascending b128 reads).
__global__ __launch_bounds__(64)
void flif_kernel(const float* __restrict__ I_old, const float* __restrict__ W,
                 float* __restrict__ out, float cm1, float c2, float c3, int Stot)
{
    const int s    = blockIdx.x;
    const int lane = threadIdx.x;

    __shared__ __align__(16) float wtr[4 * WS];     // wtr[r][k] = wt[k+r], wt[i]=wr[i+1]=W[4998-i]
    __shared__ __align__(16) float dbuf[T_STEPS];   // delta history

    const float* Irow = I_old + (size_t)s * T_STEPS;
    float Inext = Irow[lane];

    #pragma unroll
    for (int r = 0; r < 4; ++r) {
        for (int k = lane; k < WS; k += 64) {
            const int i = k + r;                     // wt[i] valid for i<=382
            wtr[r * WS + k] = (i <= 382) ? W[4998 - i] : 0.0f;
        }
    }
    // near-field seed: w0 = wr[lane] = W[4999-lane] (lane>=1), wr[0]=0
    const float w0 = (lane >= 1) ? W[4999 - lane] : 0.0f;
    __syncthreads();

    // ascending per-lane weight base: wlp[m0+q] = wt[lane+m0+q], 16B-aligned, conflict-free
    const int rl = lane & 3;
    const float* wlp = wtr + rl * WS + (lane - rl);

    float* out_spk = out + (size_t)s * T_STEPS;
    float* out_trc = out + (size_t)Stot * T_STEPS + (size_t)s * T_STEPS;

    const float wr1n = -W[4998];          // -wr[1]

    float V = 0.0f, d = 0.0f, b = 0.0f, P = 0.0f;

    for (int c = 0; c < NCH; ++c) {
        const int cb = c * CH;
        const float Ic = Inext;
        if (c + 1 < NCH) Inext = Irow[cb + CH + lane];

        // ---- far field: acc = sum_{j<cb} delta_j * wr[(cb+lane)-j], j ascending ----
        // (identical fma chain/order to R6: m0 descending, reversed in-group pairing)
        float acc = 0.0f;
        #pragma unroll 4
        for (int m0 = cb - 4; m0 >= 0; m0 -= 4) {
            const float4 d4 = *reinterpret_cast<const float4*>(dbuf + (cb - m0 - 4)); // broadcast
            const float4 w4 = *reinterpret_cast<const float4*>(wlp + m0);             // per-lane, conflict-free
            acc = fmaf(d4.x, w4.w, acc);
            acc = fmaf(d4.y, w4.z, acc);
            acc = fmaf(d4.z, w4.y, acc);
            acc = fmaf(d4.w, w4.x, acc);
        }

        float u = fmaf(c3, Ic, c2) - acc;
        const float Vs = V;
        float tc = 0.0f;
        float w = w0;                                    // wr[lane - 0]

        // steady-state step: chain is t=fma(wr1n,d,P); d=t+b; V/b/cmp path ~18cyc.
        auto body = [&](int i) {
            const float t = fmaf(wr1n, d, P);            // t_i (uniform)
            d = t + b;                                   // d_i (uniform)   [chain]
            P = readlane_f(u, (i + 1) & 63);             // u_{i-1}[i+1], pre-scatter
            V = V + d;                                   // V_i
            const float rv = (V > -50.0f) ? -20.0f : 0.0f;
            b = fmaf(cm1, V, rv);                        // b_{i+1}
            u = fmaf(-w, d, u);                          // scatter d_i forward (w = wr[lane-i])
            w = wave_shr1_f(w);                          // -> wr[lane-(i+1)], 0 in low lanes
            tc = (lane == i) ? V : tc;                   // capture trace
        };

        if (c == 0) {
            // step 0: V_prev=0 -> spike, V_pre=-70, V_new=-90; delta masked out (no scatter)
            V = -90.0f;
            if (lane == 0) tc = V;
            w = wave_shr1_f(w);                          // -> wr[lane-1]
            // step 1: V1 rule (no memory); V=-90 -> no reset
            const float I1 = readlane_f(Ic, 1);
            const float V1 = fmaf(0.005f, (I1 / 0.025f) - V, V);
            const float d1 = V1 - V;
            P = readlane_f(u, 2);
            u = fmaf(-w, d1, u);                         // scatter d_1 with wr[lane-1]
            w = wave_shr1_f(w);                          // -> wr[lane-2]
            if (lane == 1) tc = V1;
            V = V1;
            d = d1;
            const float rv = (V > -50.0f) ? -20.0f : 0.0f;
            b = fmaf(cm1, V, rv);
            #pragma unroll
            for (int i = 2; i < CH; ++i) body(i);
        } else {
            d = 0.0f;                                    // wr[1]*d_{cb-1} already in far field
            P = readlane_f(u, 0);
            #pragma unroll
            for (int i = 0; i < CH; ++i) body(i);
        }

        // ---- chunk epilogue: reconstruct prev-V per lane -> spike, delta ----
        float prev = __shfl_up(tc, 1);
        if (lane == 0) prev = Vs;
        const float spk = (prev > -50.0f) ? 1.0f : 0.0f;
        float dd = tc - prev;
        if (c == 0 && lane == 0) dd = 0.0f;              // delta_0 excluded by reference
        dbuf[cb + lane] = dd;                            // wave-local, program-ordered
        out_spk[cb + lane] = spk;
        out_trc[cb + lane] = tc;
    }
}

extern "C" void kernel_launch(void* const* d_in, const int* in_sizes, int n_in,
                              void* d_out, int out_size, void* d_ws, size_t ws_size,
                              hipStream_t stream) {
    const float* I = (const float*)d_in[0];
    const float* W = (const float*)d_in[1];
    float* out = (float*)d_out;
    const int S = in_sizes[0] / T_STEPS;   // 2048

    const double COEF = std::pow(0.1, 0.15) * std::tgamma(1.85) / 0.5;
    const float c3  = (float)COEF;                     // COEF
    const float cm1 = (float)(-COEF * 0.025);          // c1 - 1 = -COEF*GL
    const float c2  = (float)(COEF * 0.025 * -70.0);   // COEF*GL*VL

    flif_kernel<<<S, 64, 0, stream>>>(I, W, out, cm1, c2, c3, S);
}

// Round 9
// 80.737 us; speedup vs baseline: 1.0543x; 1.0543x over previous
//
#include <hip/hip_runtime.h>
#include <cmath>

#define T_STEPS 384
#define CH 64
#define NCH 6
#define WS 392   // replica stride; ascending per-lane b128 touches every bank uniformly

__device__ __forceinline__ float readlane_f(float v, int l) {
    return __int_as_float(__builtin_amdgcn_readlane(__float_as_int(v), l));
}

// DPP wave shift-right by 1: dst lane i = src lane i-1, lane 0 = 0 (bound_ctrl).
__device__ __forceinline__ float wave_shr1_f(float v) {
    return __int_as_float(__builtin_amdgcn_mov_dpp(__float_as_int(v), 0x138, 0xf, 0xf, true));
}

// Two waves per neuron (block=128), 4 waves/SIMD at full grid residency.
// Wave 0: serial 64-step chunks with the R8 DPP-marched near-field weight
// (zero register arrays, zero per-step memory ops -> NO spill at the forced
// 128-VGPR cap; this is what silently broke R7's identical structure).
// Wave 1: source-major far field -- when chunk s's deltas appear, its 16
// delta float4s are read ONCE (broadcast) and fanned into register
// accumulators At[t] for every future target t>=s+2; At[c+1] is complete
// during chunk c and handed over in LDS. Per-target accumulation order is
// j-ascending with the same group pairing and the same prefix/suffix split
// as R7/R8 -> bit-identical results (absmax must stay exactly 0.5).
__global__ __launch_bounds__(128, 4)
void flif_kernel(const float* __restrict__ I_old, const float* __restrict__ W,
                 float* __restrict__ out, float cm1, float c2, float c3, int Stot)
{
    const int tid  = threadIdx.x;
    const int wid  = tid >> 6;
    const int lane = tid & 63;
    const int s    = blockIdx.x;

    __shared__ __align__(16) float wtr[4 * WS];     // wtr[r][k] = wt[k+r], wt[i]=wr[i+1]=W[4998-i]
    __shared__ __align__(16) float dbuf[T_STEPS];   // delta history
    __shared__ float accs[2][CH];                   // g>=2 partial handoff (double-buffered)

    for (int k = tid; k < 4 * WS; k += 128) {
        const int r = k / WS, kk = k - r * WS;
        const int i = kk + r;
        wtr[k] = (i <= 382) ? W[4998 - i] : 0.0f;
    }
    ((float*)accs)[tid] = 0.0f;                      // zero both buffers (128 floats)
    __syncthreads();

    // ascending per-lane weight base: wlp[m] = wt[lane + m], 16B-aligned for m%4==0
    const int rl = lane & 3;
    const float* wlp = wtr + rl * WS + (lane - rl);

    if (wid == 1) {
        // -------- far-field producer wave (g>=2, source-major) --------
        float A2 = 0.0f, A3 = 0.0f, A4 = 0.0f, A5 = 0.0f;
        #pragma unroll
        for (int c = 0; c < NCH; ++c) {
            if (c >= 1 && c <= 4) {
                const int src = c - 1;               // deltas published at end of chunk c-1
                const float* dp = dbuf + src * CH;
                #pragma unroll
                for (int k = 0; k <= 60; k += 4) {
                    const float4 d4 = *reinterpret_cast<const float4*>(dp + k);   // broadcast, read ONCE
                    #pragma unroll
                    for (int t = c + 1; t <= 5; ++t) {
                        const int g = t - src;                                    // 2..5
                        const float4 w4 = *reinterpret_cast<const float4*>(wlp + (g * 64 - k - 4));
                        float& At = (t == 2) ? A2 : (t == 3) ? A3 : (t == 4) ? A4 : A5;
                        At = fmaf(d4.x, w4.w, At);   // j = src*64+k   (j ascending)
                        At = fmaf(d4.y, w4.z, At);
                        At = fmaf(d4.z, w4.y, At);
                        At = fmaf(d4.w, w4.x, At);
                    }
                }
                const float hand = (c == 1) ? A2 : (c == 2) ? A3 : (c == 3) ? A4 : A5;
                accs[(c + 1) & 1][lane] = hand;      // At[c+1] complete: sources 0..c-1 done
            }
            __syncthreads();
        }
        return;
    }

    // -------- step-loop wave (wid == 0) --------
    const float* Irow = I_old + (size_t)s * T_STEPS;
    float Inext = Irow[lane];
    const float w0   = (lane >= 1) ? W[4999 - lane] : 0.0f;  // wr[lane], wr[0]=0
    const float wr1n = -W[4998];                             // -wr[1]

    float V = 0.0f, d = 0.0f, b = 0.0f, P = 0.0f;
    float tcs[NCH], spks[NCH];                       // buffered outputs

    for (int c = 0; c < NCH; ++c) {
        const int cb = c * CH;
        const float Ic = Inext;
        if (c + 1 < NCH) Inext = Irow[cb + CH + lane];

        // ---- far field: g>=2 partial from producer, then append g=1 (j ascending) ----
        float acc = (c == 0) ? 0.0f : accs[c & 1][lane];
        if (c >= 1) {
            const float* dp = dbuf + (c - 1) * CH;
            #pragma unroll
            for (int m0 = 60; m0 >= 0; m0 -= 4) {
                const float4 d4 = *reinterpret_cast<const float4*>(dp + (60 - m0)); // dbuf[cb-m0-4]
                const float4 w4 = *reinterpret_cast<const float4*>(wlp + m0);
                acc = fmaf(d4.x, w4.w, acc);
                acc = fmaf(d4.y, w4.z, acc);
                acc = fmaf(d4.z, w4.y, acc);
                acc = fmaf(d4.w, w4.x, acc);
            }
        }

        float u = fmaf(c3, Ic, c2) - acc;
        const float Vs = V;
        float tc = 0.0f;
        float w = w0;                                    // wr[lane - 0]

        auto body = [&](int i) {
            const float t = fmaf(wr1n, d, P);            // t_i (uniform)
            d = t + b;                                   // d_i (uniform)   [chain]
            P = readlane_f(u, (i + 1) & 63);             // u_{i-1}[i+1], pre-scatter
            V = V + d;                                   // V_i
            const float rv = (V > -50.0f) ? -20.0f : 0.0f;
            b = fmaf(cm1, V, rv);                        // b_{i+1}
            u = fmaf(-w, d, u);                          // scatter d_i (w = wr[lane-i])
            w = wave_shr1_f(w);                          // -> wr[lane-(i+1)]
            tc = (lane == i) ? V : tc;                   // capture trace
        };

        if (c == 0) {
            // step 0: V_prev=0 -> spike, V_pre=-70, V_new=-90; delta masked out
            V = -90.0f;
            if (lane == 0) tc = V;
            w = wave_shr1_f(w);                          // -> wr[lane-1]
            // step 1: V1 rule (no memory); V=-90 -> no reset
            const float I1 = readlane_f(Ic, 1);
            const float V1 = fmaf(0.005f, (I1 / 0.025f) - V, V);
            const float d1 = V1 - V;
            P = readlane_f(u, 2);
            u = fmaf(-w, d1, u);                         // scatter d_1 with wr[lane-1]
            w = wave_shr1_f(w);                          // -> wr[lane-2]
            if (lane == 1) tc = V1;
            V = V1;
            d = d1;
            const float rv = (V > -50.0f) ? -20.0f : 0.0f;
            b = fmaf(cm1, V, rv);
            #pragma unroll
            for (int i = 2; i < CH; ++i) body(i);
        } else {
            d = 0.0f;                                    // wr[1]*d_{cb-1} already in far field
            P = readlane_f(u, 0);
            #pragma unroll
            for (int i = 0; i < CH; ++i) body(i);
        }

        // ---- chunk epilogue: prev-V per lane -> spike, delta; publish dbuf ----
        float prev = __shfl_up(tc, 1);
        if (lane == 0) prev = Vs;
        spks[c] = (prev > -50.0f) ? 1.0f : 0.0f;
        float dd = tc - prev;
        if (c == 0 && lane == 0) dd = 0.0f;              // delta_0 excluded by reference
        dbuf[cb + lane] = dd;
        tcs[c] = tc;
        __syncthreads();                                 // publish dbuf / consume accs
    }

    // ---- deferred global stores (off the barrier path) ----
    float* out_spk = out + (size_t)s * T_STEPS;
    float* out_trc = out + (size_t)Stot * T_STEPS + (size_t)s * T_STEPS;
    #pragma unroll
    for (int c = 0; c < NCH; ++c) {
        out_spk[c * CH + lane] = spks[c];
        out_trc[c * CH + lane] = tcs[c];
    }
}

extern "C" void kernel_launch(void* const* d_in, const int* in_sizes, int n_in,
                              void* d_out, int out_size, void* d_ws, size_t ws_size,
                              hipStream_t stream) {
    const float* I = (const float*)d_in[0];
    const float* W = (const float*)d_in[1];
    float* out = (float*)d_out;
    const int S = in_sizes[0] / T_STEPS;   // 2048

    const double COEF = std::pow(0.1, 0.15) * std::tgamma(1.85) / 0.5;
    const float c3  = (float)COEF;                     // COEF
    const float cm1 = (float)(-COEF * 0.025);          // c1 - 1 = -COEF*GL
    const float c2  = (float)(COEF * 0.025 * -70.0);   // COEF*GL*VL

    flif_kernel<<<S, 128, 0, stream>>>(I, W, out, cm1, c2, c3, S);
}